// Round 8
// baseline (157.807 us; speedup 1.0000x reference)
//
#include <hip/hip_runtime.h>
#include <hip/hip_bf16.h>
#include <stdint.h>

typedef unsigned short u16;
typedef __attribute__((ext_vector_type(4))) short short4v;
typedef __attribute__((ext_vector_type(8))) short short8;
typedef __attribute__((ext_vector_type(4))) float f32x4;

#define NB 2
#define NN 2048
#define ND 1024
#define NH 16
#define NR 32
#define NM (NB*NN)      // 4096 rows
#define NHR 512         // h*r
#define NQKV 1536       // 3*h*r

static __device__ __forceinline__ u16 f2bf(float f) {   // RNE
  union { float f; uint32_t u; } v; v.f = f;
  uint32_t r = v.u + 0x7fffu + ((v.u >> 16) & 1u);
  return (u16)(r >> 16);
}
static __device__ __forceinline__ u16 fastbf(float f) { // round-half-up (2 ops)
  union { float f; uint32_t u; } v; v.f = f;
  return (u16)((v.u + 0x8000u) >> 16);
}

#if __has_builtin(__builtin_amdgcn_exp2f)
#define EXP2(x) __builtin_amdgcn_exp2f(x)
#else
#define EXP2(x) __builtin_exp2f(x)
#endif

typedef __attribute__((address_space(1))) unsigned int as1_u32;
typedef __attribute__((address_space(3))) unsigned int as3_u32;

// async global->LDS, 16B per lane (wave-uniform base + lane*16, m104/m108).
static __device__ __forceinline__ void async_copy16(void* lds, const void* g) {
  __builtin_amdgcn_global_load_lds((as1_u32*)(uintptr_t)g,
                                   (as3_u32*)(uint32_t)(uintptr_t)lds,
                                   16, 0, 0);
}

// Single-barrier double-buffer ordering (r13 proof):
//   explicit "s_waitcnt vmcnt(0) lgkmcnt(0)" then __syncthreads().
//   arrival: each wave drains its own global_load_lds before arriving ->
//     after the barrier the whole tile is in LDS.
//   anti-dep: each wave drains its own ds_reads (lgkmcnt) before arriving ->
//     STAGE(kt+1) issued after the barrier can never overwrite live reads.
#define SB_BARRIER() do {                                        \
    asm volatile("s_waitcnt vmcnt(0) lgkmcnt(0)" ::: "memory");  \
    __syncthreads();                                             \
  } while (0)

// ---------------------------------------------------------------------------
// K0: fused prep -- one launch, block-partitioned (r0 structure):
//   [0,2048):    cast x fp32->bf16 (8 els/thread)
//   [2048,2304): cast Wproj
//   [2304,2496): build_wct: WcT[col][i] = sum_k W_w[h*64+k][i]*U[k][rr],
//                col = w*512+head*32+rr, Q cols scaled (1/8)*log2(e) so the
//                softmax can use v_exp_f32 (2^x) directly. U staged in LDS.
// ---------------------------------------------------------------------------
__global__ __launch_bounds__(256, 2)
void prep(const float* __restrict__ x, const float* __restrict__ Wproj,
          const float* __restrict__ Wq, const float* __restrict__ Wk,
          const float* __restrict__ Wv, const float* __restrict__ U,
          u16* __restrict__ xb, u16* __restrict__ Wpb, u16* __restrict__ WcT) {
  __shared__ float sU[64 * 32];
  const int blk = blockIdx.x;
  const int tid = threadIdx.x;
  if (blk < 2304) {                       // vector casts
    const float* in = (blk < 2048) ? x : Wproj;
    u16* o = (blk < 2048) ? xb : Wpb;
    const int i = ((blk < 2048) ? blk : (blk - 2048)) * 256 + tid;
    const float4* p = (const float4*)in + (size_t)i * 2;
    float4 a = p[0], b2 = p[1];
    short8 v;
    v[0] = f2bf(a.x);  v[1] = f2bf(a.y);  v[2] = f2bf(a.z);  v[3] = f2bf(a.w);
    v[4] = f2bf(b2.x); v[5] = f2bf(b2.y); v[6] = f2bf(b2.z); v[7] = f2bf(b2.w);
    *((short8*)o + i) = v;
  } else {                                // build_wct
    #pragma unroll
    for (int t = 0; t < 2; ++t)
      ((float4*)sU)[t * 256 + tid] = ((const float4*)U)[t * 256 + tid];
    __syncthreads();
    const int local = blk - 2304;         // 0..191
    const int wh = local >> 2;            // 0..47 = w*16+head
    const int w = wh >> 4, head = wh & 15;
    const float* W = (w == 0) ? Wq : (w == 1 ? Wk : Wv);
    const int i = (local & 3) * 256 + tid;
    const float* Wcol = W + (size_t)head * 64 * ND + i;
    float acc[32];
    #pragma unroll
    for (int rr = 0; rr < 32; ++rr) acc[rr] = 0.f;
    for (int kk = 0; kk < 64; ++kk) {
      const float wv = Wcol[(size_t)kk * ND];
      const float4* u4 = (const float4*)&sU[kk * 32];
      #pragma unroll
      for (int r4 = 0; r4 < 8; ++r4) {
        float4 u = u4[r4];
        acc[r4 * 4 + 0] += wv * u.x;
        acc[r4 * 4 + 1] += wv * u.y;
        acc[r4 * 4 + 2] += wv * u.z;
        acc[r4 * 4 + 3] += wv * u.w;
      }
    }
    // 0.125 = 1/sqrt(dk); 1.4426950408889634 = log2(e) folded for exp2-softmax
    const float sc = (w == 0) ? 0.125f * 1.44269504088896340736f : 1.0f;
    const int colBase = w * 512 + head * 32;
    #pragma unroll
    for (int rr = 0; rr < 32; ++rr)
      WcT[(size_t)(colBase + rr) * ND + i] = f2bf(acc[rr] * sc);
  }
}

// ---------------------------------------------------------------------------
// MFMA GEMM, r8: tile BM x BN templated (BM=128 fixed), BK=64:
// C = A[M x K] * BT[N x K]^T. 4 waves in 2x2 quadrants; each wave owns
// 64 x BN/2 (4 x BN/32 16x16 MFMA tiles). Per K-step per wave:
//   BN=128: 16 ds_read -> 32 MFMA (ratio 2.0); BN=64: 6 -> 16 (ratio 2.67).
// r8 rationale: gemm<0> (N=1024) at BN=128 launched only 256 blocks =
// 1 block/CU -> every SB_BARRIER drain fully exposed (m102 small-N
// collapse). BN=64 -> 512 blocks at 3 blocks/CU (48 KB LDS) restores
// inter-block overlap. gemm<1> stays BN=128 (384 blocks, 64 KB, 2/CU).
// Single-barrier double-buffered K-loop (SB_BARRIER proof above).
// LDS: ONE flat array (lA[2] | lB[2]). Staging: (BM+BN)*8 16B-chunks,
// XOR-swizzled rows, global_load_lds. XCD-rectangle swizzle (gridDim.y%8==0).
// EPI=0: fp32 store; EPI=1: QKV split-store + r5-proven vt LDS-transpose.
// ---------------------------------------------------------------------------
template<int EPI, int BN>
__global__ __launch_bounds__(256, 3)
void gemm_bt(const u16* __restrict__ A, int lda,
             const u16* __restrict__ BT, int ldb, int K,
             u16* __restrict__ o0, u16* __restrict__ o1, u16* __restrict__ o2,
             float* __restrict__ fo) {
  constexpr int BM = 128;
  constexpr int NTB = BN / 32;          // col MFMA tiles per wave
  constexpr int ACH = BM / 32;          // A staging iters (256 chunks each)
  constexpr int BCH = BN / 32;          // B staging iters
  // flat LDS: [0, 2*BM*64) = lA[2], then lB[2]
  __shared__ __align__(16) u16 lds[2 * BM * 64 + 2 * BN * 64];
  #define LA(bf) (&lds[(bf) * (BM * 64)])
  #define LB(bf) (&lds[2 * BM * 64 + (bf) * (BN * 64)])
  const int tid = threadIdx.x;
  const int lane = tid & 63, quad = lane >> 4, l16 = lane & 15;
  const int wave = tid >> 6;
  const int wr = (wave >> 1) * 64;      // wave quadrant row offset
  const int wc = (wave & 1) * (BN / 2); // wave quadrant col offset
  // XCD-rectangle swizzle
  const int GX = gridDim.x;
  const int flat = blockIdx.y * GX + blockIdx.x;
  const int xcd = flat & 7, s = flat >> 3;
  const int per = gridDim.y >> 3;
  const int brow = xcd * per + s / GX, bcol = s % GX;
  const int rowBase = brow * BM, colBase = bcol * BN;

  f32x4 acc[4][NTB];
  #pragma unroll
  for (int i = 0; i < 4; ++i)
    #pragma unroll
    for (int j = 0; j < NTB; ++j)
      acc[i][j] = (f32x4){0.f, 0.f, 0.f, 0.f};

  #define GSTAGE(t_, bf_) do {                                              \
    const int kt0 = (t_) * 64;                                              \
    _Pragma("unroll")                                                       \
    for (int it = 0; it < ACH + BCH; ++it) {                                \
      const int cid = it * 256 + tid;                                       \
      if (it < ACH) {                                                       \
        const int row = cid >> 3, pc = cid & 7;                             \
        const int gc = pc ^ (row & 7);                                      \
        async_copy16(&LA(bf_)[cid * 8],                                     \
                     &A[(size_t)(rowBase + row) * lda + kt0 + gc * 8]);     \
      } else {                                                              \
        const int c2 = cid - ACH * 256;                                     \
        const int row = c2 >> 3, pc = c2 & 7;                               \
        const int gc = pc ^ (row & 7);                                      \
        async_copy16(&LB(bf_)[c2 * 8],                                      \
                     &BT[(size_t)(colBase + row) * ldb + kt0 + gc * 8]);    \
      }                                                                     \
    }                                                                       \
  } while (0)

  const int NT = K / 64;
  GSTAGE(0, 0);
  int buf = 0;
  for (int t = 0; t < NT; ++t) {
    SB_BARRIER();                       // tile t arrived; prev reads retired
    if (t + 1 < NT) GSTAGE(t + 1, buf ^ 1);
    #pragma unroll
    for (int ks = 0; ks < 64; ks += 32) {
      short8 fa[4], fb[NTB];
      #pragma unroll
      for (int t2 = 0; t2 < 4; ++t2) {
        const int ra = wr + t2 * 16 + l16;
        const int pa = ((ks >> 3) + quad) ^ (ra & 7);
        fa[t2] = *(const short8*)&LA(buf)[ra * 64 + pa * 8];
      }
      #pragma unroll
      for (int t2 = 0; t2 < NTB; ++t2) {
        const int rb = wc + t2 * 16 + l16;
        const int pb = ((ks >> 3) + quad) ^ (rb & 7);
        fb[t2] = *(const short8*)&LB(buf)[rb * 64 + pb * 8];
      }
      #pragma unroll
      for (int mt = 0; mt < 4; ++mt)
        #pragma unroll
        for (int nt = 0; nt < NTB; ++nt)
          acc[mt][nt] = __builtin_amdgcn_mfma_f32_16x16x32_bf16(
              fa[mt], fb[nt], acc[mt][nt], 0, 0, 0);
    }
    buf ^= 1;
  }
  #undef GSTAGE

  if constexpr (EPI == 1) {
    if (colBase >= 1024) {
      // ---- vt block: LDS-transpose epilogue (coalesced stores along n) ----
      __syncthreads();                   // all waves' ds_reads retired
      u16* ldsT = &lds[0];               // BN cols x BM rows, stride 136
      const int ST = 136;                // 34816 B <= flat lds (BN=128 only)
      #pragma unroll
      for (int nt = 0; nt < NTB; ++nt) {
        const int lc = wc + nt * 16 + l16;         // local col 0..BN-1
        #pragma unroll
        for (int mt = 0; mt < 4; ++mt) {
          short4v t4;
          #pragma unroll
          for (int j = 0; j < 4; ++j) t4[j] = f2bf(acc[mt][nt][j]);
          *(short4v*)&ldsT[lc * ST + wr + mt * 16 + quad * 4] = t4;
        }
      }
      __syncthreads();
      const int b = rowBase >> 11;                 // block spans one b
      #pragma unroll
      for (int it = 0; it < 8; ++it) {
        const int chunk = it * 256 + tid;          // 0..2047 = 128 cols x 16
        const int lc = chunk >> 4, part = chunk & 15;
        const short8 vv = *(const short8*)&ldsT[lc * ST + part * 8];
        const int c = colBase + lc;
        const int head = (c >> 5) & 15, rr = c & 31;
        const int n0 = (rowBase & (NN - 1)) + part * 8;
        *(short8*)&o2[((size_t)((b * NH + head) * NR + rr)) * NN + n0] = vv;
      }
      return;
    }
  }

  #pragma unroll
  for (int mt = 0; mt < 4; ++mt) {
    const int gr0 = rowBase + wr + mt * 16 + quad * 4;
    #pragma unroll
    for (int nt = 0; nt < NTB; ++nt) {
      const int c = colBase + wc + nt * 16 + l16;
      #pragma unroll
      for (int j = 0; j < 4; ++j) {
        const float v = acc[mt][nt][j];
        const int row = gr0 + j;
        if (EPI == 0) {
          fo[(size_t)row * 1024 + c] = v;
        } else {
          const int b = row >> 11, n = row & (NN - 1);
          const int w = c >> 9, ch = c & 511, head = ch >> 5, rr = ch & 31;
          if (w == 0)
            o0[(size_t)(((b * NH + head) * NN + n)) * NR + rr] = f2bf(v);
          else
            o1[(size_t)(((b * NH + head) * NN + n)) * NR + rr] = f2bf(v);
        }
      }
    }
  }
  #undef LA
  #undef LB
}

// ---------------------------------------------------------------------------
// K3: causal flash attention. r7 structure (KVBLK=128, two sequential 64-key
// halves sharing one barrier+stage; even-qblk diagonal skips masked half).
// LDS 32 KB -> 5 blocks/CU. exp2 softmax (log2e folded into Wq scale);
// fastbf packing. Grid x = bh (32), y = reversed qblk (heavy first);
// flat&7 = bh&7 pins each (b,h)'s K/V to one XCD's L2.
// S^T = K.Q^T (C row=key-in-16=quad*4+j, col=q=l16); P^T C-layout ==
// B-operand of mfma_16x16x16 -> PV from registers. p=exp2(s') unscaled
// (|s'|<~9); masked s=-1e30 -> exp2=0; only the diagonal 64-half masks.
// ---------------------------------------------------------------------------
__global__ __launch_bounds__(256, 5)
void flash_attn(const u16* __restrict__ q, const u16* __restrict__ k,
                const u16* __restrict__ vt, u16* __restrict__ z) {
  __shared__ __align__(16) u16 lK[2][128 * 32];  // [key][r]
  __shared__ __align__(16) u16 lV[2][32 * 128];  // [r][key], chunk-swizzled
  const int bh = blockIdx.x;
  const int b = bh >> 4, head = bh & 15;
  const int tid = threadIdx.x;
  const int lane = tid & 63, quad = lane >> 4, l16 = lane & 15;
  const int wave = tid >> 6;
  const int qblk = gridDim.y - 1 - blockIdx.y;   // heavy blocks dispatch first
  const int qb0 = qblk * 64;
  const int qbase = qb0 + wave * 16;
  const int qq = qbase + l16;

  const u16* qp = q  + (size_t)bh * NN * NR;
  const u16* kp = k  + (size_t)bh * NN * NR;
  const u16* vp = vt + (size_t)bh * NR * NN;

  // B-frag of Q: B[n=q=l16][kdim=quad*8+j]
  const short8 bq = *(const short8*)&qp[(size_t)(qbase + l16) * NR + quad * 8];

  f32x4 Ot0 = (f32x4){0.f,0.f,0.f,0.f};   // O^T rows r=quad*4+j,    col q=l16
  f32x4 Ot1 = (f32x4){0.f,0.f,0.f,0.f};   // O^T rows r=16+quad*4+j
  float ls = 0.f;

  // staging: 4 chunks/thread per 128-key tile:
  //   K: 512 chunks, krow = c>>2 (0..127), kc = c&3 (4x16B per 64B row)
  //   V: 512 chunks, vrow = c>>4 (0..31), vpc = c&15 (16x16B per 256B row),
  //      source chunk pre-swizzled ^ (vrow&7) (involution; read XORs same).
  #define STAGE(kt_, buf_) do {                                               \
    const int m0_ = (kt_) * 128;                                              \
    _Pragma("unroll")                                                         \
    for (int it = 0; it < 4; ++it) {                                          \
      const int cid = it * 256 + tid;                                         \
      if (it < 2) {                                                           \
        const int krow = cid >> 2, kc = cid & 3;                              \
        async_copy16(&lK[buf_][cid * 8],                                      \
                     &kp[(size_t)(m0_ + krow) * NR + kc * 8]);                \
      } else {                                                                \
        const int c2 = cid - 512;                                             \
        const int vrow = c2 >> 4, vpc = c2 & 15;                              \
        const int sgc = vpc ^ (vrow & 7);                                     \
        async_copy16(&lV[buf_][c2 * 8],                                       \
                     &vp[(size_t)vrow * NN + m0_ + sgc * 8]);                 \
      }                                                                       \
    }                                                                         \
  } while (0)

  const int NTt = (qblk >> 1) + 1;      // 128-key tiles
  STAGE(0, 0);
  int buf = 0;
  for (int kt = 0; kt < NTt; ++kt) {
    SB_BARRIER();                    // tile kt arrived; prev reads retired
    if (kt + 1 < NTt) STAGE(kt + 1, buf ^ 1);

    #pragma unroll
    for (int half = 0; half < 2; ++half) {
      const int m0h = kt * 128 + half * 64;      // first key of this half
      if (m0h > qb0) break;                      // fully-masked half: skip
      const bool diag = (m0h == qb0);            // wave-uniform

      f32x4 s[4];
      const f32x4 zero = (f32x4){0.f,0.f,0.f,0.f};
      #pragma unroll
      for (int g = 0; g < 4; ++g) {
        const short8 ak = *(const short8*)
            &lK[buf][(half * 64 + 16 * g + l16) * 32 + quad * 8];
        s[g] = __builtin_amdgcn_mfma_f32_16x16x32_bf16(ak, bq, zero, 0, 0, 0);
      }
      if (diag) {                      // diagonal 64-half: causal mask
        #pragma unroll
        for (int g = 0; g < 4; ++g)
          #pragma unroll
          for (int j = 0; j < 4; ++j)
            if (m0h + 16 * g + quad * 4 + j > qq) s[g][j] = -1e30f;
      }
      #pragma unroll
      for (int g = 0; g < 4; ++g) {
        const float p0 = EXP2(s[g][0]), p1 = EXP2(s[g][1]);
        const float p2 = EXP2(s[g][2]), p3 = EXP2(s[g][3]);
        ls += (p0 + p1) + (p2 + p3);
        short4v bp;
        bp[0] = fastbf(p0); bp[1] = fastbf(p1);
        bp[2] = fastbf(p2); bp[3] = fastbf(p3);
        // V^T frags: row r (=l16 / 16+l16), logical chunk half*8+2g+(quad>>1)
        // (of 16 per 256B row), physical chunk ^= r&7, +4 els for odd quads.
        const int c0 = half * 8 + 2 * g + (quad >> 1), off = (quad & 1) * 4;
        const short4v av0 = *(const short4v*)
            &lV[buf][l16 * 128 + ((c0 ^ (l16 & 7)) * 8) + off];
        const short4v av1 = *(const short4v*)
            &lV[buf][(16 + l16) * 128 + ((c0 ^ ((16 + l16) & 7)) * 8) + off];
        Ot0 = __builtin_amdgcn_mfma_f32_16x16x16bf16_1k(av0, bp, Ot0, 0, 0, 0);
        Ot1 = __builtin_amdgcn_mfma_f32_16x16x16bf16_1k(av1, bp, Ot1, 0, 0, 0);
      }
    }
    buf ^= 1;
  }
  #undef STAGE

  // complete l over keys (quads hold disjoint key subsets)
  ls += __shfl_xor(ls, 16);
  ls += __shfl_xor(ls, 32);
  const float inv = 1.f / ls;

  short4v o0, o1;
  #pragma unroll
  for (int j = 0; j < 4; ++j) {
    o0[j] = f2bf(Ot0[j] * inv);
    o1[j] = f2bf(Ot1[j] * inv);
  }
  u16* zr = z + (size_t)(b * NN + qq) * NHR + head * NR;
  *(short4v*)&zr[quad * 4]      = o0;
  *(short4v*)&zr[16 + quad * 4] = o1;
}

// ---------------------------------------------------------------------------
extern "C" void kernel_launch(void* const* d_in, const int* in_sizes, int n_in,
                              void* d_out, int out_size, void* d_ws, size_t ws_size,
                              hipStream_t stream) {
  const float* x     = (const float*)d_in[0];
  // d_in[1] = mask: causal additive mask, handled analytically (unused)
  const float* Wq    = (const float*)d_in[2];
  const float* Wk    = (const float*)d_in[3];
  const float* Wv    = (const float*)d_in[4];
  const float* U     = (const float*)d_in[5];
  const float* Wproj = (const float*)d_in[6];
  // d_in[7] = rel_bias_tokens: alibi dist==0 on causal support (unused)
  float* out = (float*)d_out;

  // Workspace (24 MB), u16 units:
  //   [0,8MB)  xb (bf16 x) -- dead after gemm<1>; z (4MB) aliases it
  //   [8,9MB)  Wpb  [9,12MB) WcT  [12,24MB) q, kk, vt
  u16* ws  = (u16*)d_ws;
  u16* xb  = ws;
  u16* z   = ws;
  u16* Wpb = ws + (size_t)4 * 1024 * 1024;
  u16* WcT = Wpb + (size_t)512 * 1024;
  u16* q   = ws + (size_t)6 * 1024 * 1024;
  u16* kk  = q  + (size_t)NB * NH * NN * NR;
  u16* vt  = kk + (size_t)NB * NH * NN * NR;

  prep<<<2496, 256, 0, stream>>>(x, Wproj, Wq, Wk, Wv, U, xb, Wpb, WcT);
  gemm_bt<1, 128><<<dim3(NQKV / 128, NM / 128), 256, 0, stream>>>(
      xb, ND, WcT, ND, ND, q, kk, vt, nullptr);
  flash_attn<<<dim3(NB * NH, NN / 64), 256, 0, stream>>>(q, kk, vt, z);
  gemm_bt<0, 64><<<dim3(ND / 64, NM / 128), 256, 0, stream>>>(
      z, NHR, Wpb, NHR, NHR, nullptr, nullptr, nullptr, out);
}

// Round 9
// 151.944 us; speedup vs baseline: 1.0386x; 1.0386x over previous
//
#include <hip/hip_runtime.h>
#include <hip/hip_bf16.h>
#include <stdint.h>

typedef unsigned short u16;
typedef __attribute__((ext_vector_type(4))) short short4v;
typedef __attribute__((ext_vector_type(8))) short short8;
typedef __attribute__((ext_vector_type(4))) float f32x4;

#define NB 2
#define NN 2048
#define ND 1024
#define NH 16
#define NR 32
#define NM (NB*NN)      // 4096 rows
#define NHR 512         // h*r
#define NQKV 1536       // 3*h*r

static __device__ __forceinline__ u16 f2bf(float f) {   // RNE
  union { float f; uint32_t u; } v; v.f = f;
  uint32_t r = v.u + 0x7fffu + ((v.u >> 16) & 1u);
  return (u16)(r >> 16);
}
static __device__ __forceinline__ u16 fastbf(float f) { // round-half-up (2 ops)
  union { float f; uint32_t u; } v; v.f = f;
  return (u16)((v.u + 0x8000u) >> 16);
}

#if __has_builtin(__builtin_amdgcn_exp2f)
#define EXP2(x) __builtin_amdgcn_exp2f(x)
#else
#define EXP2(x) __builtin_exp2f(x)
#endif

typedef __attribute__((address_space(1))) unsigned int as1_u32;
typedef __attribute__((address_space(3))) unsigned int as3_u32;

// async global->LDS, 16B per lane (wave-uniform base + lane*16, m104/m108).
static __device__ __forceinline__ void async_copy16(void* lds, const void* g) {
  __builtin_amdgcn_global_load_lds((as1_u32*)(uintptr_t)g,
                                   (as3_u32*)(uint32_t)(uintptr_t)lds,
                                   16, 0, 0);
}

// Single-barrier double-buffer ordering (r13 proof):
//   explicit "s_waitcnt vmcnt(0) lgkmcnt(0)" then __syncthreads().
//   arrival: each wave drains its own global_load_lds before arriving ->
//     after the barrier the whole tile is in LDS.
//   anti-dep: each wave drains its own ds_reads (lgkmcnt) before arriving ->
//     STAGE(kt+1) issued after the barrier can never overwrite live reads.
#define SB_BARRIER() do {                                        \
    asm volatile("s_waitcnt vmcnt(0) lgkmcnt(0)" ::: "memory");  \
    __syncthreads();                                             \
  } while (0)

// ---------------------------------------------------------------------------
// K0: fused prep -- one launch, block-partitioned. r9: cast blocks coarsened
// 4x (each thread does 4 unit-stride 8-el iterations) -> 768 total blocks:
//   [0,512):   cast x fp32->bf16 (32 els/thread, 4 coalesced iters)
//   [512,576): cast Wproj (same)
//   [576,768): build_wct: WcT[col][i] = sum_k W_w[h*64+k][i]*U[k][rr],
//              col = w*512+head*32+rr, Q cols scaled (1/8)*log2(e) so the
//              softmax can use v_exp_f32 (2^x) directly. U staged in LDS.
// ---------------------------------------------------------------------------
__global__ __launch_bounds__(256, 2)
void prep(const float* __restrict__ x, const float* __restrict__ Wproj,
          const float* __restrict__ Wq, const float* __restrict__ Wk,
          const float* __restrict__ Wv, const float* __restrict__ U,
          u16* __restrict__ xb, u16* __restrict__ Wpb, u16* __restrict__ WcT) {
  __shared__ float sU[64 * 32];
  const int blk = blockIdx.x;
  const int tid = threadIdx.x;
  if (blk < 576) {                        // vector casts, 4 coalesced iters
    const float* in = (blk < 512) ? x : Wproj;
    u16* o = (blk < 512) ? xb : Wpb;
    const int base = ((blk < 512) ? blk : (blk - 512)) * 1024;
    #pragma unroll
    for (int u = 0; u < 4; ++u) {
      const int i = base + u * 256 + tid;           // 8-el chunk id
      const float4* p = (const float4*)in + (size_t)i * 2;
      float4 a = p[0], b2 = p[1];
      short8 v;
      v[0] = f2bf(a.x);  v[1] = f2bf(a.y);  v[2] = f2bf(a.z);  v[3] = f2bf(a.w);
      v[4] = f2bf(b2.x); v[5] = f2bf(b2.y); v[6] = f2bf(b2.z); v[7] = f2bf(b2.w);
      *((short8*)o + i) = v;
    }
  } else {                                // build_wct
    #pragma unroll
    for (int t = 0; t < 2; ++t)
      ((float4*)sU)[t * 256 + tid] = ((const float4*)U)[t * 256 + tid];
    __syncthreads();
    const int local = blk - 576;          // 0..191
    const int wh = local >> 2;            // 0..47 = w*16+head
    const int w = wh >> 4, head = wh & 15;
    const float* W = (w == 0) ? Wq : (w == 1 ? Wk : Wv);
    const int i = (local & 3) * 256 + tid;
    const float* Wcol = W + (size_t)head * 64 * ND + i;
    float acc[32];
    #pragma unroll
    for (int rr = 0; rr < 32; ++rr) acc[rr] = 0.f;
    for (int kk = 0; kk < 64; ++kk) {
      const float wv = Wcol[(size_t)kk * ND];
      const float4* u4 = (const float4*)&sU[kk * 32];
      #pragma unroll
      for (int r4 = 0; r4 < 8; ++r4) {
        float4 u = u4[r4];
        acc[r4 * 4 + 0] += wv * u.x;
        acc[r4 * 4 + 1] += wv * u.y;
        acc[r4 * 4 + 2] += wv * u.z;
        acc[r4 * 4 + 3] += wv * u.w;
      }
    }
    // 0.125 = 1/sqrt(dk); 1.4426950408889634 = log2(e) folded for exp2-softmax
    const float sc = (w == 0) ? 0.125f * 1.44269504088896340736f : 1.0f;
    const int colBase = w * 512 + head * 32;
    #pragma unroll
    for (int rr = 0; rr < 32; ++rr)
      WcT[(size_t)(colBase + rr) * ND + i] = f2bf(acc[rr] * sc);
  }
}

// ---------------------------------------------------------------------------
// MFMA GEMM, 128x128 tile (r6/r7-proven), BK=64: C = A[M x K] * BT[N x K]^T.
// 4 waves in 2x2 quadrants; each wave owns 64x64 (acc[4][4]); per K-step
// 16 ds_read_b128 -> 32 MFMA per wave. Single-barrier double-buffered
// K-loop (SB_BARRIER proof above). LDS: ONE flat 64 KB array -> 2 blocks/CU.
// Staging: 2048 16B-chunks, 8/thread, XOR-swizzled rows, global_load_lds.
// XCD-rectangle swizzle (gridDim.y % 8 == 0). EPI=0: fp32 store.
// EPI=1: r9 -- BOTH epilogues now LDS round-trips with 16B stores:
//   w<2 (q/kk): C staged row-major [row][col] stride-136, stores contiguous
//     along rr (was 64 scalar 2B stores/thread);
//   w==2 (vt): r5-proven transposed [col][row] stride-136, stores along n.
// ---------------------------------------------------------------------------
template<int EPI>
__global__ __launch_bounds__(256, 2)
void gemm_bt(const u16* __restrict__ A, int lda,
             const u16* __restrict__ BT, int ldb, int K,
             u16* __restrict__ o0, u16* __restrict__ o1, u16* __restrict__ o2,
             float* __restrict__ fo) {
  // flat LDS: [0,16384) = lA[2][128*64], [16384,32768) = lB[2][128*64]
  __shared__ __align__(16) u16 lds[4 * 128 * 64];
  #define LA(bf) (&lds[(bf) * (128 * 64)])
  #define LB(bf) (&lds[2 * 128 * 64 + (bf) * (128 * 64)])
  const int tid = threadIdx.x;
  const int lane = tid & 63, quad = lane >> 4, l16 = lane & 15;
  const int wave = tid >> 6;
  const int wr = (wave >> 1) * 64;      // wave quadrant row offset
  const int wc = (wave & 1) * 64;       // wave quadrant col offset
  // XCD-rectangle swizzle
  const int GX = gridDim.x;
  const int flat = blockIdx.y * GX + blockIdx.x;
  const int xcd = flat & 7, s = flat >> 3;
  const int per = gridDim.y >> 3;
  const int brow = xcd * per + s / GX, bcol = s % GX;
  const int rowBase = brow * 128, colBase = bcol * 128;

  f32x4 acc[4][4];
  #pragma unroll
  for (int i = 0; i < 4; ++i)
    #pragma unroll
    for (int j = 0; j < 4; ++j)
      acc[i][j] = (f32x4){0.f, 0.f, 0.f, 0.f};

  #define GSTAGE(t_, bf_) do {                                              \
    const int kt0 = (t_) * 64;                                              \
    _Pragma("unroll")                                                       \
    for (int it = 0; it < 8; ++it) {                                        \
      const int cid = it * 256 + tid;                                       \
      if (it < 4) {                                                         \
        const int row = cid >> 3, pc = cid & 7;                             \
        const int gc = pc ^ (row & 7);                                      \
        async_copy16(&LA(bf_)[cid * 8],                                     \
                     &A[(size_t)(rowBase + row) * lda + kt0 + gc * 8]);     \
      } else {                                                              \
        const int c2 = cid - 1024;                                          \
        const int row = c2 >> 3, pc = c2 & 7;                               \
        const int gc = pc ^ (row & 7);                                      \
        async_copy16(&LB(bf_)[c2 * 8],                                      \
                     &BT[(size_t)(colBase + row) * ldb + kt0 + gc * 8]);    \
      }                                                                     \
    }                                                                       \
  } while (0)

  const int NT = K / 64;
  GSTAGE(0, 0);
  int buf = 0;
  for (int t = 0; t < NT; ++t) {
    SB_BARRIER();                       // tile t arrived; prev reads retired
    if (t + 1 < NT) GSTAGE(t + 1, buf ^ 1);
    #pragma unroll
    for (int ks = 0; ks < 64; ks += 32) {
      short8 fa[4], fb[4];
      #pragma unroll
      for (int t2 = 0; t2 < 4; ++t2) {
        const int ra = wr + t2 * 16 + l16;
        const int pa = ((ks >> 3) + quad) ^ (ra & 7);
        fa[t2] = *(const short8*)&LA(buf)[ra * 64 + pa * 8];
      }
      #pragma unroll
      for (int t2 = 0; t2 < 4; ++t2) {
        const int rb = wc + t2 * 16 + l16;
        const int pb = ((ks >> 3) + quad) ^ (rb & 7);
        fb[t2] = *(const short8*)&LB(buf)[rb * 64 + pb * 8];
      }
      #pragma unroll
      for (int mt = 0; mt < 4; ++mt)
        #pragma unroll
        for (int nt = 0; nt < 4; ++nt)
          acc[mt][nt] = __builtin_amdgcn_mfma_f32_16x16x32_bf16(
              fa[mt], fb[nt], acc[mt][nt], 0, 0, 0);
    }
    buf ^= 1;
  }
  #undef GSTAGE

  if constexpr (EPI == 1) {
    const int ST = 136;                  // both epilogues: 34816 B <= 64 KB
    const int b = rowBase >> 11;         // 128-row tile never straddles b
    __syncthreads();                     // all waves' ds_reads retired
    if (colBase >= 1024) {
      // ---- vt block: transposed [col][row] stage, stores along n ----
      u16* ldsT = &lds[0];
      #pragma unroll
      for (int nt = 0; nt < 4; ++nt) {
        const int lc = wc + nt * 16 + l16;         // local col 0..127
        #pragma unroll
        for (int mt = 0; mt < 4; ++mt) {
          short4v t4;
          #pragma unroll
          for (int j = 0; j < 4; ++j) t4[j] = f2bf(acc[mt][nt][j]);
          *(short4v*)&ldsT[lc * ST + wr + mt * 16 + quad * 4] = t4;
        }
      }
      __syncthreads();
      #pragma unroll
      for (int it = 0; it < 8; ++it) {
        const int chunk = it * 256 + tid;          // 0..2047 = 128 cols x 16
        const int lc = chunk >> 4, part = chunk & 15;
        const short8 vv = *(const short8*)&ldsT[lc * ST + part * 8];
        const int c = colBase + lc;
        const int head = (c >> 5) & 15, rr = c & 31;
        const int n0 = (rowBase & (NN - 1)) + part * 8;
        *(short8*)&o2[((size_t)((b * NH + head) * NR + rr)) * NN + n0] = vv;
      }
    } else {
      // ---- q/kk block: row-major [row][col] stage, stores along rr ----
      u16* ldsC = &lds[0];
      u16* oq = (colBase < 512) ? o0 : o1;
      #pragma unroll
      for (int mt = 0; mt < 4; ++mt) {
        const int lr = wr + mt * 16 + quad * 4;    // local rows lr..lr+3
        #pragma unroll
        for (int nt = 0; nt < 4; ++nt) {
          const int lc = wc + nt * 16 + l16;
          #pragma unroll
          for (int j = 0; j < 4; ++j)
            ldsC[(lr + j) * ST + lc] = f2bf(acc[mt][nt][j]);
        }
      }
      __syncthreads();
      #pragma unroll
      for (int it = 0; it < 8; ++it) {
        const int chunk = it * 256 + tid;          // 0..2047 = 128 rows x 16
        const int row = chunk >> 4, part = chunk & 15;
        const short8 vv = *(const short8*)&ldsC[row * ST + part * 8];
        const int c0 = (colBase & 511) + part * 8; // 8-chunk within one head
        const int head = c0 >> 5, rr = c0 & 31;
        const int n = (rowBase & (NN - 1)) + row;
        *(short8*)&oq[((size_t)((b * NH + head) * NN + n)) * NR + rr] = vv;
      }
    }
    return;
  }

  #pragma unroll
  for (int mt = 0; mt < 4; ++mt) {
    const int gr0 = rowBase + wr + mt * 16 + quad * 4;
    #pragma unroll
    for (int nt = 0; nt < 4; ++nt) {
      const int c = colBase + wc + nt * 16 + l16;
      #pragma unroll
      for (int j = 0; j < 4; ++j)
        fo[(size_t)(gr0 + j) * 1024 + c] = acc[mt][nt][j];
    }
  }
  #undef LA
  #undef LB
}

// ---------------------------------------------------------------------------
// K3: causal flash attention. r7 structure (KVBLK=128, two sequential 64-key
// halves sharing one barrier+stage; even-qblk diagonal skips masked half).
// LDS 32 KB -> 5 blocks/CU. exp2 softmax (log2e folded into Wq scale);
// fastbf packing. Grid x = bh (32), y = reversed qblk (heavy first);
// flat&7 = bh&7 pins each (b,h)'s K/V to one XCD's L2.
// S^T = K.Q^T (C row=key-in-16=quad*4+j, col=q=l16); P^T C-layout ==
// B-operand of mfma_16x16x16 -> PV from registers. p=exp2(s') unscaled
// (|s'|<~9); masked s=-1e30 -> exp2=0; only the diagonal 64-half masks.
// ---------------------------------------------------------------------------
__global__ __launch_bounds__(256, 5)
void flash_attn(const u16* __restrict__ q, const u16* __restrict__ k,
                const u16* __restrict__ vt, u16* __restrict__ z) {
  __shared__ __align__(16) u16 lK[2][128 * 32];  // [key][r]
  __shared__ __align__(16) u16 lV[2][32 * 128];  // [r][key], chunk-swizzled
  const int bh = blockIdx.x;
  const int b = bh >> 4, head = bh & 15;
  const int tid = threadIdx.x;
  const int lane = tid & 63, quad = lane >> 4, l16 = lane & 15;
  const int wave = tid >> 6;
  const int qblk = gridDim.y - 1 - blockIdx.y;   // heavy blocks dispatch first
  const int qb0 = qblk * 64;
  const int qbase = qb0 + wave * 16;
  const int qq = qbase + l16;

  const u16* qp = q  + (size_t)bh * NN * NR;
  const u16* kp = k  + (size_t)bh * NN * NR;
  const u16* vp = vt + (size_t)bh * NR * NN;

  // B-frag of Q: B[n=q=l16][kdim=quad*8+j]
  const short8 bq = *(const short8*)&qp[(size_t)(qbase + l16) * NR + quad * 8];

  f32x4 Ot0 = (f32x4){0.f,0.f,0.f,0.f};   // O^T rows r=quad*4+j,    col q=l16
  f32x4 Ot1 = (f32x4){0.f,0.f,0.f,0.f};   // O^T rows r=16+quad*4+j
  float ls = 0.f;

  // staging: 4 chunks/thread per 128-key tile:
  //   K: 512 chunks, krow = c>>2 (0..127), kc = c&3 (4x16B per 64B row)
  //   V: 512 chunks, vrow = c>>4 (0..31), vpc = c&15 (16x16B per 256B row),
  //      source chunk pre-swizzled ^ (vrow&7) (involution; read XORs same).
  #define STAGE(kt_, buf_) do {                                               \
    const int m0_ = (kt_) * 128;                                              \
    _Pragma("unroll")                                                         \
    for (int it = 0; it < 4; ++it) {                                          \
      const int cid = it * 256 + tid;                                         \
      if (it < 2) {                                                           \
        const int krow = cid >> 2, kc = cid & 3;                              \
        async_copy16(&lK[buf_][cid * 8],                                      \
                     &kp[(size_t)(m0_ + krow) * NR + kc * 8]);                \
      } else {                                                                \
        const int c2 = cid - 512;                                             \
        const int vrow = c2 >> 4, vpc = c2 & 15;                              \
        const int sgc = vpc ^ (vrow & 7);                                     \
        async_copy16(&lV[buf_][c2 * 8],                                       \
                     &vp[(size_t)vrow * NN + m0_ + sgc * 8]);                 \
      }                                                                       \
    }                                                                         \
  } while (0)

  const int NTt = (qblk >> 1) + 1;      // 128-key tiles
  STAGE(0, 0);
  int buf = 0;
  for (int kt = 0; kt < NTt; ++kt) {
    SB_BARRIER();                    // tile kt arrived; prev reads retired
    if (kt + 1 < NTt) STAGE(kt + 1, buf ^ 1);

    #pragma unroll
    for (int half = 0; half < 2; ++half) {
      const int m0h = kt * 128 + half * 64;      // first key of this half
      if (m0h > qb0) break;                      // fully-masked half: skip
      const bool diag = (m0h == qb0);            // wave-uniform

      f32x4 s[4];
      const f32x4 zero = (f32x4){0.f,0.f,0.f,0.f};
      #pragma unroll
      for (int g = 0; g < 4; ++g) {
        const short8 ak = *(const short8*)
            &lK[buf][(half * 64 + 16 * g + l16) * 32 + quad * 8];
        s[g] = __builtin_amdgcn_mfma_f32_16x16x32_bf16(ak, bq, zero, 0, 0, 0);
      }
      if (diag) {                      // diagonal 64-half: causal mask
        #pragma unroll
        for (int g = 0; g < 4; ++g)
          #pragma unroll
          for (int j = 0; j < 4; ++j)
            if (m0h + 16 * g + quad * 4 + j > qq) s[g][j] = -1e30f;
      }
      #pragma unroll
      for (int g = 0; g < 4; ++g) {
        const float p0 = EXP2(s[g][0]), p1 = EXP2(s[g][1]);
        const float p2 = EXP2(s[g][2]), p3 = EXP2(s[g][3]);
        ls += (p0 + p1) + (p2 + p3);
        short4v bp;
        bp[0] = fastbf(p0); bp[1] = fastbf(p1);
        bp[2] = fastbf(p2); bp[3] = fastbf(p3);
        // V^T frags: row r (=l16 / 16+l16), logical chunk half*8+2g+(quad>>1)
        // (of 16 per 256B row), physical chunk ^= r&7, +4 els for odd quads.
        const int c0 = half * 8 + 2 * g + (quad >> 1), off = (quad & 1) * 4;
        const short4v av0 = *(const short4v*)
            &lV[buf][l16 * 128 + ((c0 ^ (l16 & 7)) * 8) + off];
        const short4v av1 = *(const short4v*)
            &lV[buf][(16 + l16) * 128 + ((c0 ^ ((16 + l16) & 7)) * 8) + off];
        Ot0 = __builtin_amdgcn_mfma_f32_16x16x16bf16_1k(av0, bp, Ot0, 0, 0, 0);
        Ot1 = __builtin_amdgcn_mfma_f32_16x16x16bf16_1k(av1, bp, Ot1, 0, 0, 0);
      }
    }
    buf ^= 1;
  }
  #undef STAGE

  // complete l over keys (quads hold disjoint key subsets)
  ls += __shfl_xor(ls, 16);
  ls += __shfl_xor(ls, 32);
  const float inv = 1.f / ls;

  short4v o0, o1;
  #pragma unroll
  for (int j = 0; j < 4; ++j) {
    o0[j] = f2bf(Ot0[j] * inv);
    o1[j] = f2bf(Ot1[j] * inv);
  }
  u16* zr = z + (size_t)(b * NN + qq) * NHR + head * NR;
  *(short4v*)&zr[quad * 4]      = o0;
  *(short4v*)&zr[16 + quad * 4] = o1;
}

// ---------------------------------------------------------------------------
extern "C" void kernel_launch(void* const* d_in, const int* in_sizes, int n_in,
                              void* d_out, int out_size, void* d_ws, size_t ws_size,
                              hipStream_t stream) {
  const float* x     = (const float*)d_in[0];
  // d_in[1] = mask: causal additive mask, handled analytically (unused)
  const float* Wq    = (const float*)d_in[2];
  const float* Wk    = (const float*)d_in[3];
  const float* Wv    = (const float*)d_in[4];
  const float* U     = (const float*)d_in[5];
  const float* Wproj = (const float*)d_in[6];
  // d_in[7] = rel_bias_tokens: alibi dist==0 on causal support (unused)
  float* out = (float*)d_out;

  // Workspace (24 MB), u16 units:
  //   [0,8MB)  xb (bf16 x) -- dead after gemm<1>; z (4MB) aliases it
  //   [8,9MB)  Wpb  [9,12MB) WcT  [12,24MB) q, kk, vt
  u16* ws  = (u16*)d_ws;
  u16* xb  = ws;
  u16* z   = ws;
  u16* Wpb = ws + (size_t)4 * 1024 * 1024;
  u16* WcT = Wpb + (size_t)512 * 1024;
  u16* q   = ws + (size_t)6 * 1024 * 1024;
  u16* kk  = q  + (size_t)NB * NH * NN * NR;
  u16* vt  = kk + (size_t)NB * NH * NN * NR;

  prep<<<768, 256, 0, stream>>>(x, Wproj, Wq, Wk, Wv, U, xb, Wpb, WcT);
  gemm_bt<1><<<dim3(NQKV / 128, NM / 128), 256, 0, stream>>>(
      xb, ND, WcT, ND, ND, q, kk, vt, nullptr);
  flash_attn<<<dim3(NB * NH, NN / 64), 256, 0, stream>>>(q, kk, vt, z);
  gemm_bt<0><<<dim3(ND / 128, NM / 128), 256, 0, stream>>>(
      z, NHR, Wpb, NHR, NHR, nullptr, nullptr, nullptr, out);
}